// Round 1
// baseline (6131.916 us; speedup 1.0000x reference)
//
#include <hip/hip_runtime.h>

#define BB 4
#define NN 4096
#define KK 9
#define NPTS (BB * NN)
#define EPSF 1e-5f

// ---------------------------------------------------------------- prep: transpose x -> (B,N,4) with w = |x|^2
__global__ void prep_kernel(const float* __restrict__ x, float4* __restrict__ xt4) {
    int i = blockIdx.x * 256 + threadIdx.x;           // 0..NPTS-1
    int b = i >> 12, n = i & 4095;
    float x0 = x[(b * 3 + 0) * NN + n];
    float x1 = x[(b * 3 + 1) * NN + n];
    float x2 = x[(b * 3 + 2) * NN + n];
    float s = x0 * x0 + x1 * x1 + x2 * x2;
    xt4[i] = make_float4(x0, x1, x2, s);
}

// ---------------------------------------------------------------- knn: per-thread scan, top-9 smallest d, ties -> lower index
__global__ void knn_kernel(const float4* __restrict__ xt4, int* __restrict__ idx) {
    int i = blockIdx.x * 256 + threadIdx.x;
    int b = i >> 12, n = i & 4095;
    float4 p = xt4[i];
    float bv[KK];
    int bi[KK];
#pragma unroll
    for (int j = 0; j < KK; j++) { bv[j] = 3.0e38f; bi[j] = 0x7fffffff; }
    const float4* xb = xt4 + b * NN;
    for (int m = 0; m < NN; ++m) {
        float4 q = xb[m];
        float d = p.w + q.w - 2.0f * (p.x * q.x + p.y * q.y + p.z * q.z);
        if (m == n) d += 1.0e10f;
        if (d < bv[KK - 1] || (d == bv[KK - 1] && m < bi[KK - 1])) {
            bv[KK - 1] = d; bi[KK - 1] = m;
#pragma unroll
            for (int j = KK - 1; j > 0; --j) {
                bool sw = (bv[j] < bv[j - 1]) || (bv[j] == bv[j - 1] && bi[j] < bi[j - 1]);
                if (sw) {
                    float tv = bv[j]; bv[j] = bv[j - 1]; bv[j - 1] = tv;
                    int ti = bi[j]; bi[j] = bi[j - 1]; bi[j - 1] = ti;
                }
            }
        }
    }
#pragma unroll
    for (int j = 0; j < KK; j++) idx[i * KK + j] = bi[j];
}

// ---------------------------------------------------------------- edge conv main pass
// in: (B,N,INSTRIDE) point-major. w: (COUT, 2C). Writes ymin/ymax (B,N,COUT) of y over K,
// accumulates per-channel sum/sumsq (double) into stats[64 partials][COUT] + [64][COUT].
template <int C, int COUT, int U, int INSTRIDE>
__global__ __launch_bounds__(64) void conv_kernel(const float* __restrict__ in,
                                                  const int* __restrict__ idxb,
                                                  const float* __restrict__ w,
                                                  float* __restrict__ ymin,
                                                  float* __restrict__ ymax,
                                                  double* __restrict__ stats) {
    constexpr int NT = 64;
    static_assert(COUT == NT * U, "bad U");
    __shared__ __align__(16) float sx[(KK + 1) * C];
    __shared__ int sidx[KK];
    int blk = blockIdx.x;  // b*N + n
    int t = threadIdx.x;
    if (t < KK) sidx[t] = idxb[blk * KK + t];
    __syncthreads();
    int b = blk >> 12;
    int n = blk & 4095;
    for (int e = t; e < (KK + 1) * C; e += NT) {
        int k = e / C, c = e - k * C;
        int row = (k == 0) ? n : sidx[k - 1];
        sx[e] = in[((size_t)(b << 12) + row) * INSTRIDE + c];
    }
    __syncthreads();

    const float* wr[U];
#pragma unroll
    for (int u = 0; u < U; u++) wr[u] = w + (size_t)(t + u * NT) * (2 * C);

    float base[U];
#pragma unroll
    for (int u = 0; u < U; u++) base[u] = 0.f;
    float acc[U][KK];

    if constexpr (C % 4 == 0) {
        for (int c = 0; c < C; c += 4) {
            float4 xn = *(const float4*)(sx + c);
#pragma unroll
            for (int u = 0; u < U; u++) {
                float4 wa = *(const float4*)(wr[u] + c);
                float4 wb = *(const float4*)(wr[u] + C + c);
                base[u] += (wa.x - wb.x) * xn.x + (wa.y - wb.y) * xn.y +
                           (wa.z - wb.z) * xn.z + (wa.w - wb.w) * xn.w;
            }
        }
#pragma unroll
        for (int u = 0; u < U; u++)
#pragma unroll
            for (int k = 0; k < KK; k++) acc[u][k] = base[u];
        for (int c = 0; c < C; c += 4) {
            float4 xj[KK];
#pragma unroll
            for (int k = 0; k < KK; k++) xj[k] = *(const float4*)(sx + (k + 1) * C + c);
#pragma unroll
            for (int u = 0; u < U; u++) {
                float4 wb = *(const float4*)(wr[u] + C + c);
#pragma unroll
                for (int k = 0; k < KK; k++)
                    acc[u][k] += wb.x * xj[k].x + wb.y * xj[k].y + wb.z * xj[k].z + wb.w * xj[k].w;
            }
        }
    } else {
        // C == 3 path (layer 1)
#pragma unroll
        for (int c = 0; c < C; c++) {
            float xn = sx[c];
#pragma unroll
            for (int u = 0; u < U; u++) base[u] += (wr[u][c] - wr[u][C + c]) * xn;
        }
#pragma unroll
        for (int u = 0; u < U; u++)
#pragma unroll
            for (int k = 0; k < KK; k++) acc[u][k] = base[u];
#pragma unroll
        for (int c = 0; c < C; c++) {
#pragma unroll
            for (int u = 0; u < U; u++) {
                float wb = wr[u][C + c];
#pragma unroll
                for (int k = 0; k < KK; k++) acc[u][k] += wb * sx[(k + 1) * C + c];
            }
        }
    }

    int part = blk & 63;
#pragma unroll
    for (int u = 0; u < U; u++) {
        int o = t + u * NT;
        float mx = acc[u][0], mn = acc[u][0], s = 0.f, s2 = 0.f;
#pragma unroll
        for (int k = 0; k < KK; k++) {
            float v = acc[u][k];
            mx = fmaxf(mx, v);
            mn = fminf(mn, v);
            s += v;
            s2 += v * v;
        }
        size_t oidx = (size_t)blk * COUT + o;
        ymin[oidx] = mn;
        ymax[oidx] = mx;
        atomicAdd(&stats[part * COUT + o], (double)s);
        atomicAdd(&stats[64 * COUT + part * COUT + o], (double)s2);
    }
}

// ---------------------------------------------------------------- finalize BN stats -> scale/shift
template <int COUT>
__global__ void finalize_kernel(const double* __restrict__ stats, const float* __restrict__ g,
                                const float* __restrict__ bias, float* __restrict__ ss,
                                float count) {
    int o = threadIdx.x;
    if (o >= COUT) return;
    double s = 0.0, s2 = 0.0;
    for (int p = 0; p < 64; p++) {
        s += stats[p * COUT + o];
        s2 += stats[64 * COUT + p * COUT + o];
    }
    double m = s / (double)count;
    double var = s2 / (double)count - m * m;
    float scale = g[o] * rsqrtf((float)var + EPSF);
    ss[o] = scale;
    ss[COUT + o] = bias[o] - (float)m * scale;
}

// ---------------------------------------------------------------- apply: relu(scale * (scale>=0 ? ymax : ymin) + shift)
template <int COUT>
__global__ void apply_kernel(const float* __restrict__ ymin, const float* __restrict__ ymax,
                             const float* __restrict__ ss, float* __restrict__ out, int total) {
    int i = blockIdx.x * 256 + threadIdx.x;
    if (i >= total) return;
    int o = i & (COUT - 1);
    float s = ss[o], sh = ss[COUT + o];
    float v = (s >= 0.f) ? ymax[i] : ymin[i];
    out[i] = fmaxf(fmaf(s, v, sh), 0.f);
}

// ---------------------------------------------------------------- decoder: z = dec_w (48,64) @ act1 row
__global__ __launch_bounds__(64) void dec_kernel(const float* __restrict__ act1,
                                                 const float* __restrict__ w,
                                                 float* __restrict__ z,
                                                 double* __restrict__ stats) {
    __shared__ __align__(16) float sx[64];
    int blk = blockIdx.x;
    int t = threadIdx.x;
    sx[t] = act1[(size_t)blk * 64 + t];
    __syncthreads();
    if (t < 48) {
        const float* wr = w + t * 64;
        float acc = 0.f;
#pragma unroll
        for (int c = 0; c < 64; c += 4) {
            float4 wv = *(const float4*)(wr + c);
            float4 xv = *(const float4*)(sx + c);
            acc += wv.x * xv.x + wv.y * xv.y + wv.z * xv.z + wv.w * xv.w;
        }
        z[(size_t)blk * 48 + t] = acc;
        int part = blk & 63;
        atomicAdd(&stats[part * 48 + t], (double)acc);
        atomicAdd(&stats[64 * 48 + part * 48 + t], (double)acc * (double)acc);
    }
}

__global__ void decapply_kernel(const float* __restrict__ z, const float* __restrict__ ss,
                                float* __restrict__ low) {
    int i = blockIdx.x * 256 + threadIdx.x;
    if (i >= NPTS * 48) return;
    int o = i % 48;
    float s = ss[o], sh = ss[48 + o];
    low[i] = fmaxf(fmaf(s, z[i], sh), 0.f);
}

// ---------------------------------------------------------------- fused = fus_w (256,304) @ [act4;low]
__global__ __launch_bounds__(64) void fused_kernel(const float* __restrict__ act4,
                                                   const float* __restrict__ low,
                                                   const float* __restrict__ fw,
                                                   float* __restrict__ fused) {
    __shared__ __align__(16) float sx[304];
    int blk = blockIdx.x, t = threadIdx.x;
    const float* a = act4 + (size_t)blk * 256;
    for (int e = t; e < 256; e += 64) sx[e] = a[e];
    if (t < 48) sx[256 + t] = low[(size_t)blk * 48 + t];
    __syncthreads();
#pragma unroll
    for (int u = 0; u < 4; u++) {
        int o = t + u * 64;
        const float* wr = fw + (size_t)o * 304;
        float acc = 0.f;
        for (int c = 0; c < 304; c += 4) {
            float4 wv = *(const float4*)(wr + c);
            float4 xv = *(const float4*)(sx + c);
            acc += wv.x * xv.x + wv.y * xv.y + wv.z * xv.z + wv.w * xv.w;
        }
        fused[(size_t)blk * 256 + o] = acc;
    }
}

// ---------------------------------------------------------------- fused reduce over n: max + sum, 2 stages
__global__ void fusedred1_kernel(const float* __restrict__ fused, float* __restrict__ pmax,
                                 double* __restrict__ psum) {
    int blk = blockIdx.x;           // b*16 + tile
    int b = blk >> 4, tile = blk & 15;
    int o = threadIdx.x;
    const float* f = fused + ((size_t)b * NN + tile * 256) * 256 + o;
    float mx = -3.0e38f;
    double s = 0.0;
    for (int n = 0; n < 256; n++) {
        float v = f[(size_t)n * 256];
        mx = fmaxf(mx, v);
        s += (double)v;
    }
    pmax[blk * 256 + o] = mx;
    psum[blk * 256 + o] = s;
}

__global__ void fusedred2_kernel(const float* __restrict__ pmax, const double* __restrict__ psum,
                                 float* __restrict__ h) {
    int b = blockIdx.x, o = threadIdx.x;
    float mx = -3.0e38f;
    double s = 0.0;
    for (int t = 0; t < 16; t++) {
        mx = fmaxf(mx, pmax[(b * 16 + t) * 256 + o]);
        s += psum[(b * 16 + t) * 256 + o];
    }
    h[b * 512 + o] = mx;
    h[b * 512 + 256 + o] = (float)(s * (1.0 / 4096.0));
}

// ---------------------------------------------------------------- classifier (single block)
__global__ __launch_bounds__(256) void cls_kernel(const float* __restrict__ h,
                                                  const float* __restrict__ w1,
                                                  const float* __restrict__ g,
                                                  const float* __restrict__ bias,
                                                  const float* __restrict__ w2,
                                                  float* __restrict__ out) {
    __shared__ __align__(16) float sh[4 * 512];
    __shared__ __align__(16) float sh2[4 * 256];
    int t = threadIdx.x;
    for (int e = t; e < 2048; e += 256) sh[e] = h[e];
    __syncthreads();
    float y[4];
    const float* wr = w1 + (size_t)t * 512;
#pragma unroll
    for (int b2 = 0; b2 < 4; b2++) {
        float acc = 0.f;
        for (int c = 0; c < 512; c += 4) {
            float4 wv = *(const float4*)(wr + c);
            acc += wv.x * sh[b2 * 512 + c] + wv.y * sh[b2 * 512 + c + 1] +
                   wv.z * sh[b2 * 512 + c + 2] + wv.w * sh[b2 * 512 + c + 3];
        }
        y[b2] = acc;
    }
    float m = 0.25f * (y[0] + y[1] + y[2] + y[3]);
    float v = 0.25f * ((y[0] - m) * (y[0] - m) + (y[1] - m) * (y[1] - m) +
                       (y[2] - m) * (y[2] - m) + (y[3] - m) * (y[3] - m));
    float sc = g[t] * rsqrtf(v + EPSF);
    float shf = bias[t] - m * sc;
#pragma unroll
    for (int b2 = 0; b2 < 4; b2++) sh2[b2 * 256 + t] = fmaxf(fmaf(sc, y[b2], shf), 0.f);
    __syncthreads();
    if (t < 160) {
        int b2 = t / 40, j = t % 40;
        const float* wr2 = w2 + j * 256;
        float acc = 0.f;
        for (int c = 0; c < 256; c += 4) {
            float4 wv = *(const float4*)(wr2 + c);
            acc += wv.x * sh2[b2 * 256 + c] + wv.y * sh2[b2 * 256 + c + 1] +
                   wv.z * sh2[b2 * 256 + c + 2] + wv.w * sh2[b2 * 256 + c + 3];
        }
        out[b2 * 40 + j] = acc;
    }
}

// ----------------------------------------------------------------
extern "C" void kernel_launch(void* const* d_in, const int* in_sizes, int n_in,
                              void* d_out, int out_size, void* d_ws, size_t ws_size,
                              hipStream_t stream) {
    const float* x = (const float*)d_in[0];
    const float* w1 = (const float*)d_in[2];
    const float* g1 = (const float*)d_in[3];
    const float* b1 = (const float*)d_in[4];
    const float* w2 = (const float*)d_in[5];
    const float* g2 = (const float*)d_in[6];
    const float* b2 = (const float*)d_in[7];
    const float* w3 = (const float*)d_in[8];
    const float* g3 = (const float*)d_in[9];
    const float* b3 = (const float*)d_in[10];
    const float* w4 = (const float*)d_in[11];
    const float* g4 = (const float*)d_in[12];
    const float* b4 = (const float*)d_in[13];
    const float* dec_w = (const float*)d_in[14];
    const float* dec_g = (const float*)d_in[15];
    const float* dec_b = (const float*)d_in[16];
    const float* fus_w = (const float*)d_in[17];
    const float* cls_w1 = (const float*)d_in[18];
    const float* cls_g = (const float*)d_in[19];
    const float* cls_b = (const float*)d_in[20];
    const float* cls_w2 = (const float*)d_in[21];
    float* out = (float*)d_out;

    char* ws = (char*)d_ws;
    size_t cur = 0;
    auto alloc = [&](size_t bytes) -> void* {
        void* p = ws + cur;
        cur += (bytes + 255) & ~(size_t)255;
        return p;
    };
    // stats doubles first (8-byte aligned at base)
    const size_t STATS_DBL = 96256;  // 64*(64+128+256+256+48)*2
    double* stats = (double*)alloc(STATS_DBL * 8);
    const size_t OFF1 = 0, OFF2 = 8192, OFF3 = 24576, OFF4 = 57344, OFFD = 90112;
    float4* xt4 = (float4*)alloc((size_t)NPTS * 16);
    int* idx = (int*)alloc((size_t)NPTS * KK * 4);
    float* act1 = (float*)alloc((size_t)NPTS * 64 * 4);
    float* act2 = (float*)alloc((size_t)NPTS * 128 * 4);
    float* act3 = (float*)alloc((size_t)NPTS * 256 * 4);  // reused later for `fused`
    float* act4 = (float*)alloc((size_t)NPTS * 256 * 4);
    float* zdec = (float*)alloc((size_t)NPTS * 48 * 4);
    float* low = (float*)alloc((size_t)NPTS * 48 * 4);
    float* ymin = (float*)alloc((size_t)NPTS * 256 * 4);
    float* ymax = (float*)alloc((size_t)NPTS * 256 * 4);
    float* hbuf = (float*)alloc(2048 * 4);
    float* ss = (float*)alloc(2048 * 4);
    const size_t SS1 = 0, SS2 = 128, SS3 = 384, SS4 = 896, SSD = 1408;
    float* pmax = (float*)alloc(64 * 256 * 4);
    double* psum2 = (double*)alloc(64 * 256 * 8);

    hipMemsetAsync(stats, 0, STATS_DBL * 8, stream);

    prep_kernel<<<NPTS / 256, 256, 0, stream>>>(x, xt4);
    knn_kernel<<<NPTS / 256, 256, 0, stream>>>(xt4, idx);

    // layer 1: C=3 (stride 4), COUT=64
    conv_kernel<3, 64, 1, 4><<<NPTS, 64, 0, stream>>>((const float*)xt4, idx, w1, ymin, ymax, stats + OFF1);
    finalize_kernel<64><<<1, 64, 0, stream>>>(stats + OFF1, g1, b1, ss + SS1, 147456.f);
    apply_kernel<64><<<NPTS * 64 / 256, 256, 0, stream>>>(ymin, ymax, ss + SS1, act1, NPTS * 64);

    // layer 2: C=64 -> 128
    conv_kernel<64, 128, 2, 64><<<NPTS, 64, 0, stream>>>(act1, idx, w2, ymin, ymax, stats + OFF2);
    finalize_kernel<128><<<1, 128, 0, stream>>>(stats + OFF2, g2, b2, ss + SS2, 147456.f);
    apply_kernel<128><<<NPTS * 128 / 256, 256, 0, stream>>>(ymin, ymax, ss + SS2, act2, NPTS * 128);

    // layer 3: C=128 -> 256
    conv_kernel<128, 256, 4, 128><<<NPTS, 64, 0, stream>>>(act2, idx, w3, ymin, ymax, stats + OFF3);
    finalize_kernel<256><<<1, 256, 0, stream>>>(stats + OFF3, g3, b3, ss + SS3, 147456.f);
    apply_kernel<256><<<NPTS * 256 / 256, 256, 0, stream>>>(ymin, ymax, ss + SS3, act3, NPTS * 256);

    // layer 4: C=256 -> 256
    conv_kernel<256, 256, 4, 256><<<NPTS, 64, 0, stream>>>(act3, idx, w4, ymin, ymax, stats + OFF4);
    finalize_kernel<256><<<1, 256, 0, stream>>>(stats + OFF4, g4, b4, ss + SS4, 147456.f);
    apply_kernel<256><<<NPTS * 256 / 256, 256, 0, stream>>>(ymin, ymax, ss + SS4, act4, NPTS * 256);

    // decoder on act1
    dec_kernel<<<NPTS, 64, 0, stream>>>(act1, dec_w, zdec, stats + OFFD);
    finalize_kernel<48><<<1, 64, 0, stream>>>(stats + OFFD, dec_g, dec_b, ss + SSD, 16384.f);
    decapply_kernel<<<(NPTS * 48 + 255) / 256, 256, 0, stream>>>(zdec, ss + SSD, low);

    // fusion + global pooling + classifier
    fused_kernel<<<NPTS, 64, 0, stream>>>(act4, low, fus_w, act3 /* reuse as fused */);
    fusedred1_kernel<<<64, 256, 0, stream>>>(act3, pmax, psum2);
    fusedred2_kernel<<<4, 256, 0, stream>>>(pmax, psum2, hbuf);
    cls_kernel<<<1, 256, 0, stream>>>(hbuf, cls_w1, cls_g, cls_b, cls_w2, out);
}

// Round 3
// 1389.017 us; speedup vs baseline: 4.4146x; 4.4146x over previous
//
#include <hip/hip_runtime.h>

#define BB 4
#define NN 4096
#define KK 9
#define NPTS (BB * NN)
#define EPSF 1e-5f

// ---------------------------------------------------------------- prep: transpose x -> (B,N,4) with w = |x|^2
__global__ void prep_kernel(const float* __restrict__ x, float4* __restrict__ xt4) {
    int i = blockIdx.x * 256 + threadIdx.x;  // 0..NPTS-1
    int b = i >> 12, n = i & 4095;
    float x0 = x[(b * 3 + 0) * NN + n];
    float x1 = x[(b * 3 + 1) * NN + n];
    float x2 = x[(b * 3 + 2) * NN + n];
    float s = x0 * x0 + x1 * x1 + x2 * x2;
    xt4[i] = make_float4(x0, x1, x2, s);
}

// ---------------------------------------------------------------- knn: 4-way K-split scan + LDS merge
// 256 threads = 64 queries x 4 chunks of 1024 points. Ties -> lower index (top_k stable).
__global__ __launch_bounds__(256) void knn_kernel(const float4* __restrict__ xt4, int* __restrict__ idx) {
    __shared__ float sbv[4][64][KK];
    __shared__ int sbi[4][64][KK];
    int tid = threadIdx.x;
    int q = tid & 63, ch = tid >> 6;
    int blk = blockIdx.x;       // 256 blocks: 64 per batch
    int b = blk >> 6;
    int n = ((blk & 63) << 6) + q;  // query index within batch
    const float4* xb = xt4 + (b << 12);
    float4 p = xb[n];
    float bv[KK];
    int bi[KK];
#pragma unroll
    for (int j = 0; j < KK; j++) { bv[j] = 3.0e38f; bi[j] = 0x7fffffff; }
    int m0 = ch << 10;
    for (int m = m0; m < m0 + 1024; ++m) {
        float4 qq = xb[m];
        float d = p.w + qq.w - 2.0f * (p.x * qq.x + p.y * qq.y + p.z * qq.z);
        if (m == n) d += 1.0e10f;
        if (d < bv[KK - 1] || (d == bv[KK - 1] && m < bi[KK - 1])) {
            bv[KK - 1] = d; bi[KK - 1] = m;
#pragma unroll
            for (int j = KK - 1; j > 0; --j) {
                bool sw = (bv[j] < bv[j - 1]) || (bv[j] == bv[j - 1] && bi[j] < bi[j - 1]);
                if (sw) {
                    float tv = bv[j]; bv[j] = bv[j - 1]; bv[j - 1] = tv;
                    int ti = bi[j]; bi[j] = bi[j - 1]; bi[j - 1] = ti;
                }
            }
        }
    }
#pragma unroll
    for (int j = 0; j < KK; j++) { sbv[ch][q][j] = bv[j]; sbi[ch][q][j] = bi[j]; }
    __syncthreads();
    if (tid < 64) {
        int h[4] = {0, 0, 0, 0};
        size_t obase = ((size_t)(b << 12) + ((blk & 63) << 6) + tid) * KK;
#pragma unroll
        for (int j = 0; j < KK; j++) {
            int best = 0;
            float bestv = sbv[0][tid][h[0]];
            int besti = sbi[0][tid][h[0]];
#pragma unroll
            for (int c = 1; c < 4; c++) {
                float v = sbv[c][tid][h[c]];
                int i2 = sbi[c][tid][h[c]];
                if (v < bestv || (v == bestv && i2 < besti)) { best = c; bestv = v; besti = i2; }
            }
            idx[obase + j] = besti;
            h[best]++;
        }
    }
}

// ---------------------------------------------------------------- weight prep: w (COUT x 2C) -> wc (2COUT x C): [w1-w2; w2]
__global__ void wprep_kernel(const float* __restrict__ w, float* __restrict__ wc, int COUT, int C) {
    int i = blockIdx.x * 256 + threadIdx.x;
    if (i >= COUT * C) return;
    int o = i / C, c = i - o * C;
    float a = w[o * 2 * C + c], b = w[o * 2 * C + C + c];
    wc[o * C + c] = a - b;
    wc[(COUT + o) * C + c] = b;
}

// ---------------------------------------------------------------- generic fp32 GEMM: Out[m, j] = sum_c A[m, c] * Bw[j, c]
// A: (16384 x LDA) row-major (uses K_ cols). Bw: (N x K_) row-major. Out: (16384 x ldo).
// grid = (128, N/128), block = 256, tile 128x128x16, 8x8 per thread.
template <int K_, int LDA>
__global__ __launch_bounds__(256) void gemm_kernel(const float* __restrict__ A,
                                                   const float* __restrict__ Bw,
                                                   float* __restrict__ Out, int ldo) {
    constexpr int BK = 16;
    constexpr int LDS_S = 132;  // padded stride
    __shared__ float sA[BK * LDS_S];
    __shared__ float sB[BK * LDS_S];
    int tid = threadIdx.x;
    int m0 = blockIdx.x * 128;
    int n0 = blockIdx.y * 128;
    int lrow = tid >> 2;        // 0..63
    int kq = (tid & 3) * 4;     // 0,4,8,12
    int tm = (tid & 15) * 8;
    int tn = (tid >> 4) * 8;

    float acc[8][8];
#pragma unroll
    for (int i = 0; i < 8; i++)
#pragma unroll
        for (int j = 0; j < 8; j++) acc[i][j] = 0.f;

    for (int k0 = 0; k0 < K_; k0 += BK) {
        // load A tile (rows lrow, lrow+64) and B tile, transposed into LDS
#pragma unroll
        for (int h = 0; h < 2; h++) {
            int r = lrow + h * 64;
            float4 va = *(const float4*)(A + (size_t)(m0 + r) * LDA + k0 + kq);
            sA[(kq + 0) * LDS_S + r] = va.x;
            sA[(kq + 1) * LDS_S + r] = va.y;
            sA[(kq + 2) * LDS_S + r] = va.z;
            sA[(kq + 3) * LDS_S + r] = va.w;
            float4 vb = *(const float4*)(Bw + (size_t)(n0 + r) * K_ + k0 + kq);
            sB[(kq + 0) * LDS_S + r] = vb.x;
            sB[(kq + 1) * LDS_S + r] = vb.y;
            sB[(kq + 2) * LDS_S + r] = vb.z;
            sB[(kq + 3) * LDS_S + r] = vb.w;
        }
        __syncthreads();
#pragma unroll 4
        for (int k = 0; k < BK; k++) {
            float4 a0 = *(const float4*)(sA + k * LDS_S + tm);
            float4 a1 = *(const float4*)(sA + k * LDS_S + tm + 4);
            float4 b0 = *(const float4*)(sB + k * LDS_S + tn);
            float4 b1 = *(const float4*)(sB + k * LDS_S + tn + 4);
            float av[8] = {a0.x, a0.y, a0.z, a0.w, a1.x, a1.y, a1.z, a1.w};
            float bv[8] = {b0.x, b0.y, b0.z, b0.w, b1.x, b1.y, b1.z, b1.w};
#pragma unroll
            for (int i = 0; i < 8; i++)
#pragma unroll
                for (int j = 0; j < 8; j++) acc[i][j] = fmaf(av[i], bv[j], acc[i][j]);
        }
        __syncthreads();
    }
#pragma unroll
    for (int i = 0; i < 8; i++) {
        float4 o0 = make_float4(acc[i][0], acc[i][1], acc[i][2], acc[i][3]);
        float4 o1 = make_float4(acc[i][4], acc[i][5], acc[i][6], acc[i][7]);
        float* orow = Out + (size_t)(m0 + tm + i) * ldo + n0 + tn;
        *(float4*)(orow) = o0;
        *(float4*)(orow + 4) = o1;
    }
}

// ---------------------------------------------------------------- layer-1 GEMM (K=3): G1[m, j] = xt4[m] . wc1[j]
__global__ __launch_bounds__(256) void gemm3_kernel(const float4* __restrict__ xt4,
                                                    const float* __restrict__ wc,
                                                    float* __restrict__ G) {
    __shared__ float sw[128 * 3];
    int tid = threadIdx.x;
    for (int e = tid; e < 128 * 3; e += 256) sw[e] = wc[e];
    __syncthreads();
    int i = blockIdx.x * 256 + tid;  // over 16384*128
    int m = i >> 7, j = i & 127;
    float4 xp = xt4[m];
    G[i] = xp.x * sw[j * 3 + 0] + xp.y * sw[j * 3 + 1] + xp.z * sw[j * 3 + 2];
}

// ---------------------------------------------------------------- gather + K-reduce + stats
// G: (NPTS x 2*COUT) [base | z]. y_k[o] = base[o] + z[b*4096 + idx[k]][o]; min/max over k, stats sum/sumsq.
template <int COUT>
__global__ __launch_bounds__(256) void gather_kernel(const float* __restrict__ G,
                                                     const int* __restrict__ idxb,
                                                     float* __restrict__ ymin,
                                                     float* __restrict__ ymax,
                                                     double* __restrict__ stats) {
    int t = threadIdx.x & 63;
    int p = threadIdx.x >> 6;
    int n = blockIdx.x * 4 + p;  // point id (global, 0..NPTS-1)
    int bbase = n & ~4095;       // batch row offset (idx values are within-batch)
    int nb[KK];
#pragma unroll
    for (int k = 0; k < KK; k++) nb[k] = bbase + idxb[n * KK + k];
    const float* gb = G + (size_t)n * (2 * COUT);
    int part = n & 63;
#pragma unroll
    for (int u = 0; u < COUT / 64; u++) {
        int o = t + u * 64;
        float base = gb[o];
        float mn = 3.0e38f, mx = -3.0e38f, s = 0.f, s2 = 0.f;
#pragma unroll
        for (int k = 0; k < KK; k++) {
            float v = base + G[(size_t)nb[k] * (2 * COUT) + COUT + o];
            mn = fminf(mn, v);
            mx = fmaxf(mx, v);
            s += v;
            s2 += v * v;
        }
        size_t oidx = (size_t)n * COUT + o;
        ymin[oidx] = mn;
        ymax[oidx] = mx;
        atomicAdd(&stats[part * COUT + o], (double)s);
        atomicAdd(&stats[64 * COUT + part * COUT + o], (double)s2);
    }
}

// ---------------------------------------------------------------- finalize BN stats -> scale/shift
template <int COUT>
__global__ void finalize_kernel(const double* __restrict__ stats, const float* __restrict__ g,
                                const float* __restrict__ bias, float* __restrict__ ss,
                                float count) {
    int o = threadIdx.x;
    if (o >= COUT) return;
    double s = 0.0, s2 = 0.0;
    for (int p = 0; p < 64; p++) {
        s += stats[p * COUT + o];
        s2 += stats[64 * COUT + p * COUT + o];
    }
    double m = s / (double)count;
    double var = s2 / (double)count - m * m;
    float scale = g[o] * rsqrtf((float)var + EPSF);
    ss[o] = scale;
    ss[COUT + o] = bias[o] - (float)m * scale;
}

// ---------------------------------------------------------------- apply: relu(scale * (scale>=0 ? ymax : ymin) + shift)
template <int COUT>
__global__ void apply_kernel(const float* __restrict__ ymin, const float* __restrict__ ymax,
                             const float* __restrict__ ss, float* __restrict__ out, int ldo) {
    int i = blockIdx.x * 256 + threadIdx.x;  // over NPTS*COUT
    int o = i & (COUT - 1);
    int n = i / COUT;
    float s = ss[o], sh = ss[COUT + o];
    float v = (s >= 0.f) ? ymax[i] : ymin[i];
    out[(size_t)n * ldo + o] = fmaxf(fmaf(s, v, sh), 0.f);
}

// ---------------------------------------------------------------- decoder: z = dec_w (48,64) @ act1 row
__global__ __launch_bounds__(64) void dec_kernel(const float* __restrict__ act1,
                                                 const float* __restrict__ w,
                                                 float* __restrict__ z,
                                                 double* __restrict__ stats) {
    __shared__ __align__(16) float sx[64];
    int blk = blockIdx.x;
    int t = threadIdx.x;
    sx[t] = act1[(size_t)blk * 64 + t];
    __syncthreads();
    if (t < 48) {
        const float* wr = w + t * 64;
        float acc = 0.f;
#pragma unroll
        for (int c = 0; c < 64; c += 4) {
            float4 wv = *(const float4*)(wr + c);
            float4 xv = *(const float4*)(sx + c);
            acc += wv.x * xv.x + wv.y * xv.y + wv.z * xv.z + wv.w * xv.w;
        }
        z[(size_t)blk * 48 + t] = acc;
        int part = blk & 63;
        atomicAdd(&stats[part * 48 + t], (double)acc);
        atomicAdd(&stats[64 * 48 + part * 48 + t], (double)acc * (double)acc);
    }
}

// decapply writes low into actf columns 256..303 (stride 304)
__global__ void decapply_kernel(const float* __restrict__ z, const float* __restrict__ ss,
                                float* __restrict__ actf) {
    int i = blockIdx.x * 256 + threadIdx.x;
    if (i >= NPTS * 48) return;
    int n = i / 48, o = i - n * 48;
    float s = ss[o], sh = ss[48 + o];
    actf[(size_t)n * 304 + 256 + o] = fmaxf(fmaf(s, z[i], sh), 0.f);
}

// ---------------------------------------------------------------- fused reduce over n: max + sum, 2 stages
__global__ void fusedred1_kernel(const float* __restrict__ fused, float* __restrict__ pmax,
                                 double* __restrict__ psum) {
    int blk = blockIdx.x;  // b*16 + tile
    int b = blk >> 4, tile = blk & 15;
    int o = threadIdx.x;
    const float* f = fused + ((size_t)b * NN + tile * 256) * 256 + o;
    float mx = -3.0e38f;
    double s = 0.0;
    for (int n = 0; n < 256; n++) {
        float v = f[(size_t)n * 256];
        mx = fmaxf(mx, v);
        s += (double)v;
    }
    pmax[blk * 256 + o] = mx;
    psum[blk * 256 + o] = s;
}

__global__ void fusedred2_kernel(const float* __restrict__ pmax, const double* __restrict__ psum,
                                 float* __restrict__ h) {
    int b = blockIdx.x, o = threadIdx.x;
    float mx = -3.0e38f;
    double s = 0.0;
    for (int t = 0; t < 16; t++) {
        mx = fmaxf(mx, pmax[(b * 16 + t) * 256 + o]);
        s += psum[(b * 16 + t) * 256 + o];
    }
    h[b * 512 + o] = mx;
    h[b * 512 + 256 + o] = (float)(s * (1.0 / 4096.0));
}

// ---------------------------------------------------------------- classifier (single block)
__global__ __launch_bounds__(256) void cls_kernel(const float* __restrict__ h,
                                                  const float* __restrict__ w1,
                                                  const float* __restrict__ g,
                                                  const float* __restrict__ bias,
                                                  const float* __restrict__ w2,
                                                  float* __restrict__ out) {
    __shared__ __align__(16) float sh[4 * 512];
    __shared__ __align__(16) float sh2[4 * 256];
    int t = threadIdx.x;
    for (int e = t; e < 2048; e += 256) sh[e] = h[e];
    __syncthreads();
    float y[4];
    const float* wr = w1 + (size_t)t * 512;
#pragma unroll
    for (int b2 = 0; b2 < 4; b2++) {
        float acc = 0.f;
        for (int c = 0; c < 512; c += 4) {
            float4 wv = *(const float4*)(wr + c);
            acc += wv.x * sh[b2 * 512 + c] + wv.y * sh[b2 * 512 + c + 1] +
                   wv.z * sh[b2 * 512 + c + 2] + wv.w * sh[b2 * 512 + c + 3];
        }
        y[b2] = acc;
    }
    float m = 0.25f * (y[0] + y[1] + y[2] + y[3]);
    float v = 0.25f * ((y[0] - m) * (y[0] - m) + (y[1] - m) * (y[1] - m) +
                       (y[2] - m) * (y[2] - m) + (y[3] - m) * (y[3] - m));
    float sc = g[t] * rsqrtf(v + EPSF);
    float shf = bias[t] - m * sc;
#pragma unroll
    for (int b2 = 0; b2 < 4; b2++) sh2[b2 * 256 + t] = fmaxf(fmaf(sc, y[b2], shf), 0.f);
    __syncthreads();
    if (t < 160) {
        int b2 = t / 40, j = t % 40;
        const float* wr2 = w2 + j * 256;
        float acc = 0.f;
        for (int c = 0; c < 256; c += 4) {
            float4 wv = *(const float4*)(wr2 + c);
            acc += wv.x * sh2[b2 * 256 + c] + wv.y * sh2[b2 * 256 + c + 1] +
                   wv.z * sh2[b2 * 256 + c + 2] + wv.w * sh2[b2 * 256 + c + 3];
        }
        out[b2 * 40 + j] = acc;
    }
}

// ----------------------------------------------------------------
extern "C" void kernel_launch(void* const* d_in, const int* in_sizes, int n_in,
                              void* d_out, int out_size, void* d_ws, size_t ws_size,
                              hipStream_t stream) {
    const float* x = (const float*)d_in[0];
    const float* w1 = (const float*)d_in[2];
    const float* g1 = (const float*)d_in[3];
    const float* b1 = (const float*)d_in[4];
    const float* w2 = (const float*)d_in[5];
    const float* g2 = (const float*)d_in[6];
    const float* b2 = (const float*)d_in[7];
    const float* w3 = (const float*)d_in[8];
    const float* g3 = (const float*)d_in[9];
    const float* b3 = (const float*)d_in[10];
    const float* w4 = (const float*)d_in[11];
    const float* g4 = (const float*)d_in[12];
    const float* b4 = (const float*)d_in[13];
    const float* dec_w = (const float*)d_in[14];
    const float* dec_g = (const float*)d_in[15];
    const float* dec_b = (const float*)d_in[16];
    const float* fus_w = (const float*)d_in[17];
    const float* cls_w1 = (const float*)d_in[18];
    const float* cls_g = (const float*)d_in[19];
    const float* cls_b = (const float*)d_in[20];
    const float* cls_w2 = (const float*)d_in[21];
    float* out = (float*)d_out;

    char* ws = (char*)d_ws;
    size_t cur = 0;
    auto alloc = [&](size_t bytes) -> void* {
        void* p = ws + cur;
        cur += (bytes + 255) & ~(size_t)255;
        return p;
    };
    const size_t STATS_DBL = 96256;  // 64*(64+128+256+256+48)*2
    double* stats = (double*)alloc(STATS_DBL * 8);
    const size_t OFF1 = 0, OFF2 = 8192, OFF3 = 24576, OFF4 = 57344, OFFD = 90112;
    float4* xt4 = (float4*)alloc((size_t)NPTS * 16);
    int* idx = (int*)alloc((size_t)NPTS * KK * 4);
    float* act1 = (float*)alloc((size_t)NPTS * 64 * 4);
    float* act2 = (float*)alloc((size_t)NPTS * 128 * 4);
    float* act3 = (float*)alloc((size_t)NPTS * 256 * 4);
    float* actf = (float*)alloc((size_t)NPTS * 304 * 4);  // [act4 | low]
    float* G = (float*)alloc((size_t)NPTS * 512 * 4);     // GEMM out [base|z]; reused for fused out
    float* zdec = (float*)alloc((size_t)NPTS * 48 * 4);
    float* ymin = (float*)alloc((size_t)NPTS * 256 * 4);
    float* ymax = (float*)alloc((size_t)NPTS * 256 * 4);
    float* hbuf = (float*)alloc(2048 * 4);
    float* ss = (float*)alloc(2048 * 4);
    const size_t SS1 = 0, SS2 = 128, SS3 = 384, SS4 = 896, SSD = 1408;
    float* pmax = (float*)alloc(64 * 256 * 4);
    double* psum2 = (double*)alloc(64 * 256 * 8);
    float* wc1 = (float*)alloc(128 * 3 * 4);
    float* wc2 = (float*)alloc(256 * 64 * 4);
    float* wc3 = (float*)alloc(512 * 128 * 4);
    float* wc4 = (float*)alloc(512 * 256 * 4);

    hipMemsetAsync(stats, 0, STATS_DBL * 8, stream);

    prep_kernel<<<NPTS / 256, 256, 0, stream>>>(x, xt4);
    knn_kernel<<<NPTS / 64, 256, 0, stream>>>(xt4, idx);

    wprep_kernel<<<(64 * 3 + 255) / 256, 256, 0, stream>>>(w1, wc1, 64, 3);
    wprep_kernel<<<(128 * 64 + 255) / 256, 256, 0, stream>>>(w2, wc2, 128, 64);
    wprep_kernel<<<(256 * 128 + 255) / 256, 256, 0, stream>>>(w3, wc3, 256, 128);
    wprep_kernel<<<(256 * 256 + 255) / 256, 256, 0, stream>>>(w4, wc4, 256, 256);

    // layer 1: K=3 -> G1 (16384 x 128)
    gemm3_kernel<<<NPTS * 128 / 256, 256, 0, stream>>>(xt4, wc1, G);
    gather_kernel<64><<<NPTS / 4, 256, 0, stream>>>(G, idx, ymin, ymax, stats + OFF1);
    finalize_kernel<64><<<1, 64, 0, stream>>>(stats + OFF1, g1, b1, ss + SS1, 147456.f);
    apply_kernel<64><<<NPTS * 64 / 256, 256, 0, stream>>>(ymin, ymax, ss + SS1, act1, 64);

    // layer 2: 64 -> 128 (N = 256)
    gemm_kernel<64, 64><<<dim3(128, 2), 256, 0, stream>>>(act1, wc2, G, 256);
    gather_kernel<128><<<NPTS / 4, 256, 0, stream>>>(G, idx, ymin, ymax, stats + OFF2);
    finalize_kernel<128><<<1, 128, 0, stream>>>(stats + OFF2, g2, b2, ss + SS2, 147456.f);
    apply_kernel<128><<<NPTS * 128 / 256, 256, 0, stream>>>(ymin, ymax, ss + SS2, act2, 128);

    // layer 3: 128 -> 256 (N = 512)
    gemm_kernel<128, 128><<<dim3(128, 4), 256, 0, stream>>>(act2, wc3, G, 512);
    gather_kernel<256><<<NPTS / 4, 256, 0, stream>>>(G, idx, ymin, ymax, stats + OFF3);
    finalize_kernel<256><<<1, 256, 0, stream>>>(stats + OFF3, g3, b3, ss + SS3, 147456.f);
    apply_kernel<256><<<NPTS * 256 / 256, 256, 0, stream>>>(ymin, ymax, ss + SS3, act3, 256);

    // layer 4: 256 -> 256 (N = 512), act into actf cols 0..255
    gemm_kernel<256, 256><<<dim3(128, 4), 256, 0, stream>>>(act3, wc4, G, 512);
    gather_kernel<256><<<NPTS / 4, 256, 0, stream>>>(G, idx, ymin, ymax, stats + OFF4);
    finalize_kernel<256><<<1, 256, 0, stream>>>(stats + OFF4, g4, b4, ss + SS4, 147456.f);
    apply_kernel<256><<<NPTS * 256 / 256, 256, 0, stream>>>(ymin, ymax, ss + SS4, actf, 304);

    // decoder on act1 -> actf cols 256..303
    dec_kernel<<<NPTS, 64, 0, stream>>>(act1, dec_w, zdec, stats + OFFD);
    finalize_kernel<48><<<1, 64, 0, stream>>>(stats + OFFD, dec_g, dec_b, ss + SSD, 16384.f);
    decapply_kernel<<<(NPTS * 48 + 255) / 256, 256, 0, stream>>>(zdec, ss + SSD, actf);

    // fusion GEMM: fus_w (256 x 304) @ actf -> G (16384 x 256)
    gemm_kernel<304, 304><<<dim3(128, 2), 256, 0, stream>>>(actf, fus_w, G, 256);
    fusedred1_kernel<<<64, 256, 0, stream>>>(G, pmax, psum2);
    fusedred2_kernel<<<4, 256, 0, stream>>>(pmax, psum2, hbuf);
    cls_kernel<<<1, 256, 0, stream>>>(hbuf, cls_w1, cls_g, cls_b, cls_w2, out);
}

// Round 4
// 990.019 us; speedup vs baseline: 6.1937x; 1.4030x over previous
//
#include <hip/hip_runtime.h>

#define BB 4
#define NN 4096
#define KK 9
#define NPTS (BB * NN)
#define EPSF 1e-5f

// ---------------------------------------------------------------- prep: transpose x -> (B,N,4) with w = |x|^2
__global__ void prep_kernel(const float* __restrict__ x, float4* __restrict__ xt4) {
    int i = blockIdx.x * 256 + threadIdx.x;  // 0..NPTS-1
    int b = i >> 12, n = i & 4095;
    float x0 = x[(b * 3 + 0) * NN + n];
    float x1 = x[(b * 3 + 1) * NN + n];
    float x2 = x[(b * 3 + 2) * NN + n];
    float s = x0 * x0 + x1 * x1 + x2 * x2;
    xt4[i] = make_float4(x0, x1, x2, s);
}

// ---------------------------------------------------------------- knn: 16 queries x 16 chunks(256 pts) per block + stable LDS merge
// grid = NPTS/16 = 1024 blocks -> 4 blocks/CU, 16 waves/CU. Ties -> lower index (top_k stable).
__global__ __launch_bounds__(256) void knn_kernel(const float4* __restrict__ xt4, int* __restrict__ idx) {
    __shared__ float sbv[16][16][10];
    __shared__ int sbi[16][16][10];
    int tid = threadIdx.x;
    int q = tid & 15;        // query within block
    int ch = tid >> 4;       // chunk 0..15
    int blk = blockIdx.x;    // 1024 blocks: 256 per batch
    int b = blk >> 8;
    int qbase = (blk & 255) << 4;
    int n = qbase + q;       // within-batch query index
    const float4* xb = xt4 + (b << 12);
    float4 p = xb[n];
    float bv[KK];
    int bi[KK];
#pragma unroll
    for (int j = 0; j < KK; j++) { bv[j] = 3.0e38f; bi[j] = 0x7fffffff; }
    int m0 = ch << 8;
    for (int m = m0; m < m0 + 256; ++m) {
        float4 qq = xb[m];
        float d = p.w + qq.w - 2.0f * (p.x * qq.x + p.y * qq.y + p.z * qq.z);
        if (m == n) d += 1.0e10f;
        if (d < bv[KK - 1] || (d == bv[KK - 1] && m < bi[KK - 1])) {
            bv[KK - 1] = d; bi[KK - 1] = m;
#pragma unroll
            for (int j = KK - 1; j > 0; --j) {
                bool sw = (bv[j] < bv[j - 1]) || (bv[j] == bv[j - 1] && bi[j] < bi[j - 1]);
                if (sw) {
                    float tv = bv[j]; bv[j] = bv[j - 1]; bv[j - 1] = tv;
                    int ti = bi[j]; bi[j] = bi[j - 1]; bi[j - 1] = ti;
                }
            }
        }
    }
#pragma unroll
    for (int j = 0; j < KK; j++) { sbv[ch][q][j] = bv[j]; sbi[ch][q][j] = bi[j]; }
    sbv[ch][q][KK] = 3.0e38f;      // sentinel for consumed lists
    sbi[ch][q][KK] = 0x7fffffff;
    __syncthreads();
    if (tid < 16) {
        int h[16];
#pragma unroll
        for (int c = 0; c < 16; c++) h[c] = 0;
        size_t obase = ((size_t)(b << 12) + qbase + tid) * KK;
#pragma unroll
        for (int j = 0; j < KK; j++) {
            int bestc = 0;
            float bestv = sbv[0][tid][h[0]];
            int besti = sbi[0][tid][h[0]];
#pragma unroll
            for (int c = 1; c < 16; c++) {
                float v = sbv[c][tid][h[c]];
                int i2 = sbi[c][tid][h[c]];
                if (v < bestv || (v == bestv && i2 < besti)) { bestc = c; bestv = v; besti = i2; }
            }
            idx[obase + j] = besti;
#pragma unroll
            for (int c = 0; c < 16; c++) h[c] += (c == bestc) ? 1 : 0;
        }
    }
}

// ---------------------------------------------------------------- weight prep: w (COUT x 2C) -> wc (2COUT x C): [w1-w2; w2]
__global__ void wprep_kernel(const float* __restrict__ w, float* __restrict__ wc, int COUT, int C) {
    int i = blockIdx.x * 256 + threadIdx.x;
    if (i >= COUT * C) return;
    int o = i / C, c = i - o * C;
    float a = w[o * 2 * C + c], b = w[o * 2 * C + C + c];
    wc[o * C + c] = a - b;
    wc[(COUT + o) * C + c] = b;
}

// ---------------------------------------------------------------- generic fp32 GEMM: Out[m, j] = sum_c A[m, c] * Bw[j, c]
// A: (16384 x LDA) row-major (uses K_ cols). Bw: (N x K_) row-major. Out: (16384 x ldo).
// grid = (128, N/128), block = 256, tile 128x128x16, 8x8 per thread.
template <int K_, int LDA>
__global__ __launch_bounds__(256) void gemm_kernel(const float* __restrict__ A,
                                                   const float* __restrict__ Bw,
                                                   float* __restrict__ Out, int ldo) {
    constexpr int BK = 16;
    constexpr int LDS_S = 132;  // padded stride
    __shared__ float sA[BK * LDS_S];
    __shared__ float sB[BK * LDS_S];
    int tid = threadIdx.x;
    int m0 = blockIdx.x * 128;
    int n0 = blockIdx.y * 128;
    int lrow = tid >> 2;        // 0..63
    int kq = (tid & 3) * 4;     // 0,4,8,12
    int tm = (tid & 15) * 8;
    int tn = (tid >> 4) * 8;

    float acc[8][8];
#pragma unroll
    for (int i = 0; i < 8; i++)
#pragma unroll
        for (int j = 0; j < 8; j++) acc[i][j] = 0.f;

    for (int k0 = 0; k0 < K_; k0 += BK) {
        // load A tile (rows lrow, lrow+64) and B tile, transposed into LDS
#pragma unroll
        for (int h = 0; h < 2; h++) {
            int r = lrow + h * 64;
            float4 va = *(const float4*)(A + (size_t)(m0 + r) * LDA + k0 + kq);
            sA[(kq + 0) * LDS_S + r] = va.x;
            sA[(kq + 1) * LDS_S + r] = va.y;
            sA[(kq + 2) * LDS_S + r] = va.z;
            sA[(kq + 3) * LDS_S + r] = va.w;
            float4 vb = *(const float4*)(Bw + (size_t)(n0 + r) * K_ + k0 + kq);
            sB[(kq + 0) * LDS_S + r] = vb.x;
            sB[(kq + 1) * LDS_S + r] = vb.y;
            sB[(kq + 2) * LDS_S + r] = vb.z;
            sB[(kq + 3) * LDS_S + r] = vb.w;
        }
        __syncthreads();
#pragma unroll 4
        for (int k = 0; k < BK; k++) {
            float4 a0 = *(const float4*)(sA + k * LDS_S + tm);
            float4 a1 = *(const float4*)(sA + k * LDS_S + tm + 4);
            float4 b0 = *(const float4*)(sB + k * LDS_S + tn);
            float4 b1 = *(const float4*)(sB + k * LDS_S + tn + 4);
            float av[8] = {a0.x, a0.y, a0.z, a0.w, a1.x, a1.y, a1.z, a1.w};
            float bv[8] = {b0.x, b0.y, b0.z, b0.w, b1.x, b1.y, b1.z, b1.w};
#pragma unroll
            for (int i = 0; i < 8; i++)
#pragma unroll
                for (int j = 0; j < 8; j++) acc[i][j] = fmaf(av[i], bv[j], acc[i][j]);
        }
        __syncthreads();
    }
#pragma unroll
    for (int i = 0; i < 8; i++) {
        float4 o0 = make_float4(acc[i][0], acc[i][1], acc[i][2], acc[i][3]);
        float4 o1 = make_float4(acc[i][4], acc[i][5], acc[i][6], acc[i][7]);
        float* orow = Out + (size_t)(m0 + tm + i) * ldo + n0 + tn;
        *(float4*)(orow) = o0;
        *(float4*)(orow + 4) = o1;
    }
}

// ---------------------------------------------------------------- layer-1 GEMM (K=3): G1[m, j] = xt4[m] . wc1[j]
__global__ __launch_bounds__(256) void gemm3_kernel(const float4* __restrict__ xt4,
                                                    const float* __restrict__ wc,
                                                    float* __restrict__ G) {
    __shared__ float sw[128 * 3];
    int tid = threadIdx.x;
    for (int e = tid; e < 128 * 3; e += 256) sw[e] = wc[e];
    __syncthreads();
    int i = blockIdx.x * 256 + tid;  // over 16384*128
    int m = i >> 7, j = i & 127;
    float4 xp = xt4[m];
    G[i] = xp.x * sw[j * 3 + 0] + xp.y * sw[j * 3 + 1] + xp.z * sw[j * 3 + 2];
}

// ---------------------------------------------------------------- gather + K-reduce + stats
// G: (NPTS x 2*COUT) [base | z]. y_k[o] = base[o] + z[b*4096 + idx[k]][o]; min/max over k, stats sum/sumsq.
template <int COUT>
__global__ __launch_bounds__(256) void gather_kernel(const float* __restrict__ G,
                                                     const int* __restrict__ idxb,
                                                     float* __restrict__ ymin,
                                                     float* __restrict__ ymax,
                                                     double* __restrict__ stats) {
    int t = threadIdx.x & 63;
    int p = threadIdx.x >> 6;
    int n = blockIdx.x * 4 + p;  // point id (global, 0..NPTS-1)
    int bbase = n & ~4095;       // batch row offset (idx values are within-batch)
    int nb[KK];
#pragma unroll
    for (int k = 0; k < KK; k++) nb[k] = bbase + idxb[n * KK + k];
    const float* gb = G + (size_t)n * (2 * COUT);
    int part = n & 63;
#pragma unroll
    for (int u = 0; u < COUT / 64; u++) {
        int o = t + u * 64;
        float base = gb[o];
        float mn = 3.0e38f, mx = -3.0e38f, s = 0.f, s2 = 0.f;
#pragma unroll
        for (int k = 0; k < KK; k++) {
            float v = base + G[(size_t)nb[k] * (2 * COUT) + COUT + o];
            mn = fminf(mn, v);
            mx = fmaxf(mx, v);
            s += v;
            s2 += v * v;
        }
        size_t oidx = (size_t)n * COUT + o;
        ymin[oidx] = mn;
        ymax[oidx] = mx;
        atomicAdd(&stats[part * COUT + o], (double)s);
        atomicAdd(&stats[64 * COUT + part * COUT + o], (double)s2);
    }
}

// ---------------------------------------------------------------- finalize BN stats -> scale/shift
template <int COUT>
__global__ void finalize_kernel(const double* __restrict__ stats, const float* __restrict__ g,
                                const float* __restrict__ bias, float* __restrict__ ss,
                                float count) {
    int o = threadIdx.x;
    if (o >= COUT) return;
    double s = 0.0, s2 = 0.0;
    for (int p = 0; p < 64; p++) {
        s += stats[p * COUT + o];
        s2 += stats[64 * COUT + p * COUT + o];
    }
    double m = s / (double)count;
    double var = s2 / (double)count - m * m;
    float scale = g[o] * rsqrtf((float)var + EPSF);
    ss[o] = scale;
    ss[COUT + o] = bias[o] - (float)m * scale;
}

// ---------------------------------------------------------------- apply: relu(scale * (scale>=0 ? ymax : ymin) + shift)
template <int COUT>
__global__ void apply_kernel(const float* __restrict__ ymin, const float* __restrict__ ymax,
                             const float* __restrict__ ss, float* __restrict__ out, int ldo) {
    int i = blockIdx.x * 256 + threadIdx.x;  // over NPTS*COUT
    int o = i & (COUT - 1);
    int n = i / COUT;
    float s = ss[o], sh = ss[COUT + o];
    float v = (s >= 0.f) ? ymax[i] : ymin[i];
    out[(size_t)n * ldo + o] = fmaxf(fmaf(s, v, sh), 0.f);
}

// ---------------------------------------------------------------- decoder: z = dec_w (48,64) @ act1 row
__global__ __launch_bounds__(64) void dec_kernel(const float* __restrict__ act1,
                                                 const float* __restrict__ w,
                                                 float* __restrict__ z,
                                                 double* __restrict__ stats) {
    __shared__ __align__(16) float sx[64];
    int blk = blockIdx.x;
    int t = threadIdx.x;
    sx[t] = act1[(size_t)blk * 64 + t];
    __syncthreads();
    if (t < 48) {
        const float* wr = w + t * 64;
        float acc = 0.f;
#pragma unroll
        for (int c = 0; c < 64; c += 4) {
            float4 wv = *(const float4*)(wr + c);
            float4 xv = *(const float4*)(sx + c);
            acc += wv.x * xv.x + wv.y * xv.y + wv.z * xv.z + wv.w * xv.w;
        }
        z[(size_t)blk * 48 + t] = acc;
        int part = blk & 63;
        atomicAdd(&stats[part * 48 + t], (double)acc);
        atomicAdd(&stats[64 * 48 + part * 48 + t], (double)acc * (double)acc);
    }
}

// decapply writes low into actf columns 256..303 (stride 304)
__global__ void decapply_kernel(const float* __restrict__ z, const float* __restrict__ ss,
                                float* __restrict__ actf) {
    int i = blockIdx.x * 256 + threadIdx.x;
    if (i >= NPTS * 48) return;
    int n = i / 48, o = i - n * 48;
    float s = ss[o], sh = ss[48 + o];
    actf[(size_t)n * 304 + 256 + o] = fmaxf(fmaf(s, z[i], sh), 0.f);
}

// ---------------------------------------------------------------- fused reduce over n: max + sum, 2 stages
__global__ void fusedred1_kernel(const float* __restrict__ fused, float* __restrict__ pmax,
                                 double* __restrict__ psum) {
    int blk = blockIdx.x;  // b*16 + tile
    int b = blk >> 4, tile = blk & 15;
    int o = threadIdx.x;
    const float* f = fused + ((size_t)b * NN + tile * 256) * 256 + o;
    float mx = -3.0e38f;
    double s = 0.0;
    for (int n = 0; n < 256; n++) {
        float v = f[(size_t)n * 256];
        mx = fmaxf(mx, v);
        s += (double)v;
    }
    pmax[blk * 256 + o] = mx;
    psum[blk * 256 + o] = s;
}

__global__ void fusedred2_kernel(const float* __restrict__ pmax, const double* __restrict__ psum,
                                 float* __restrict__ h) {
    int b = blockIdx.x, o = threadIdx.x;
    float mx = -3.0e38f;
    double s = 0.0;
    for (int t = 0; t < 16; t++) {
        mx = fmaxf(mx, pmax[(b * 16 + t) * 256 + o]);
        s += psum[(b * 16 + t) * 256 + o];
    }
    h[b * 512 + o] = mx;
    h[b * 512 + 256 + o] = (float)(s * (1.0 / 4096.0));
}

// ---------------------------------------------------------------- classifier (single block)
__global__ __launch_bounds__(256) void cls_kernel(const float* __restrict__ h,
                                                  const float* __restrict__ w1,
                                                  const float* __restrict__ g,
                                                  const float* __restrict__ bias,
                                                  const float* __restrict__ w2,
                                                  float* __restrict__ out) {
    __shared__ __align__(16) float sh[4 * 512];
    __shared__ __align__(16) float sh2[4 * 256];
    int t = threadIdx.x;
    for (int e = t; e < 2048; e += 256) sh[e] = h[e];
    __syncthreads();
    float y[4];
    const float* wr = w1 + (size_t)t * 512;
#pragma unroll
    for (int b2 = 0; b2 < 4; b2++) {
        float acc = 0.f;
        for (int c = 0; c < 512; c += 4) {
            float4 wv = *(const float4*)(wr + c);
            acc += wv.x * sh[b2 * 512 + c] + wv.y * sh[b2 * 512 + c + 1] +
                   wv.z * sh[b2 * 512 + c + 2] + wv.w * sh[b2 * 512 + c + 3];
        }
        y[b2] = acc;
    }
    float m = 0.25f * (y[0] + y[1] + y[2] + y[3]);
    float v = 0.25f * ((y[0] - m) * (y[0] - m) + (y[1] - m) * (y[1] - m) +
                       (y[2] - m) * (y[2] - m) + (y[3] - m) * (y[3] - m));
    float sc = g[t] * rsqrtf(v + EPSF);
    float shf = bias[t] - m * sc;
#pragma unroll
    for (int b2 = 0; b2 < 4; b2++) sh2[b2 * 256 + t] = fmaxf(fmaf(sc, y[b2], shf), 0.f);
    __syncthreads();
    if (t < 160) {
        int b2 = t / 40, j = t % 40;
        const float* wr2 = w2 + j * 256;
        float acc = 0.f;
        for (int c = 0; c < 256; c += 4) {
            float4 wv = *(const float4*)(wr2 + c);
            acc += wv.x * sh2[b2 * 256 + c] + wv.y * sh2[b2 * 256 + c + 1] +
                   wv.z * sh2[b2 * 256 + c + 2] + wv.w * sh2[b2 * 256 + c + 3];
        }
        out[b2 * 40 + j] = acc;
    }
}

// ----------------------------------------------------------------
extern "C" void kernel_launch(void* const* d_in, const int* in_sizes, int n_in,
                              void* d_out, int out_size, void* d_ws, size_t ws_size,
                              hipStream_t stream) {
    const float* x = (const float*)d_in[0];
    const float* w1 = (const float*)d_in[2];
    const float* g1 = (const float*)d_in[3];
    const float* b1 = (const float*)d_in[4];
    const float* w2 = (const float*)d_in[5];
    const float* g2 = (const float*)d_in[6];
    const float* b2 = (const float*)d_in[7];
    const float* w3 = (const float*)d_in[8];
    const float* g3 = (const float*)d_in[9];
    const float* b3 = (const float*)d_in[10];
    const float* w4 = (const float*)d_in[11];
    const float* g4 = (const float*)d_in[12];
    const float* b4 = (const float*)d_in[13];
    const float* dec_w = (const float*)d_in[14];
    const float* dec_g = (const float*)d_in[15];
    const float* dec_b = (const float*)d_in[16];
    const float* fus_w = (const float*)d_in[17];
    const float* cls_w1 = (const float*)d_in[18];
    const float* cls_g = (const float*)d_in[19];
    const float* cls_b = (const float*)d_in[20];
    const float* cls_w2 = (const float*)d_in[21];
    float* out = (float*)d_out;

    char* ws = (char*)d_ws;
    size_t cur = 0;
    auto alloc = [&](size_t bytes) -> void* {
        void* p = ws + cur;
        cur += (bytes + 255) & ~(size_t)255;
        return p;
    };
    const size_t STATS_DBL = 96256;  // 64*(64+128+256+256+48)*2
    double* stats = (double*)alloc(STATS_DBL * 8);
    const size_t OFF1 = 0, OFF2 = 8192, OFF3 = 24576, OFF4 = 57344, OFFD = 90112;
    float4* xt4 = (float4*)alloc((size_t)NPTS * 16);
    int* idx = (int*)alloc((size_t)NPTS * KK * 4);
    float* act1 = (float*)alloc((size_t)NPTS * 64 * 4);
    float* act2 = (float*)alloc((size_t)NPTS * 128 * 4);
    float* act3 = (float*)alloc((size_t)NPTS * 256 * 4);
    float* actf = (float*)alloc((size_t)NPTS * 304 * 4);  // [act4 | low]
    float* G = (float*)alloc((size_t)NPTS * 512 * 4);     // GEMM out [base|z]; reused for fused out
    float* zdec = (float*)alloc((size_t)NPTS * 48 * 4);
    float* ymin = (float*)alloc((size_t)NPTS * 256 * 4);
    float* ymax = (float*)alloc((size_t)NPTS * 256 * 4);
    float* hbuf = (float*)alloc(2048 * 4);
    float* ss = (float*)alloc(2048 * 4);
    const size_t SS1 = 0, SS2 = 128, SS3 = 384, SS4 = 896, SSD = 1408;
    float* pmax = (float*)alloc(64 * 256 * 4);
    double* psum2 = (double*)alloc(64 * 256 * 8);
    float* wc1 = (float*)alloc(128 * 3 * 4);
    float* wc2 = (float*)alloc(256 * 64 * 4);
    float* wc3 = (float*)alloc(512 * 128 * 4);
    float* wc4 = (float*)alloc(512 * 256 * 4);

    hipMemsetAsync(stats, 0, STATS_DBL * 8, stream);

    prep_kernel<<<NPTS / 256, 256, 0, stream>>>(x, xt4);
    knn_kernel<<<NPTS / 16, 256, 0, stream>>>(xt4, idx);

    wprep_kernel<<<(64 * 3 + 255) / 256, 256, 0, stream>>>(w1, wc1, 64, 3);
    wprep_kernel<<<(128 * 64 + 255) / 256, 256, 0, stream>>>(w2, wc2, 128, 64);
    wprep_kernel<<<(256 * 128 + 255) / 256, 256, 0, stream>>>(w3, wc3, 256, 128);
    wprep_kernel<<<(256 * 256 + 255) / 256, 256, 0, stream>>>(w4, wc4, 256, 256);

    // layer 1: K=3 -> G1 (16384 x 128)
    gemm3_kernel<<<NPTS * 128 / 256, 256, 0, stream>>>(xt4, wc1, G);
    gather_kernel<64><<<NPTS / 4, 256, 0, stream>>>(G, idx, ymin, ymax, stats + OFF1);
    finalize_kernel<64><<<1, 64, 0, stream>>>(stats + OFF1, g1, b1, ss + SS1, 147456.f);
    apply_kernel<64><<<NPTS * 64 / 256, 256, 0, stream>>>(ymin, ymax, ss + SS1, act1, 64);

    // layer 2: 64 -> 128 (N = 256)
    gemm_kernel<64, 64><<<dim3(128, 2), 256, 0, stream>>>(act1, wc2, G, 256);
    gather_kernel<128><<<NPTS / 4, 256, 0, stream>>>(G, idx, ymin, ymax, stats + OFF2);
    finalize_kernel<128><<<1, 128, 0, stream>>>(stats + OFF2, g2, b2, ss + SS2, 147456.f);
    apply_kernel<128><<<NPTS * 128 / 256, 256, 0, stream>>>(ymin, ymax, ss + SS2, act2, 128);

    // layer 3: 128 -> 256 (N = 512)
    gemm_kernel<128, 128><<<dim3(128, 4), 256, 0, stream>>>(act2, wc3, G, 512);
    gather_kernel<256><<<NPTS / 4, 256, 0, stream>>>(G, idx, ymin, ymax, stats + OFF3);
    finalize_kernel<256><<<1, 256, 0, stream>>>(stats + OFF3, g3, b3, ss + SS3, 147456.f);
    apply_kernel<256><<<NPTS * 256 / 256, 256, 0, stream>>>(ymin, ymax, ss + SS3, act3, 256);

    // layer 4: 256 -> 256 (N = 512), act into actf cols 0..255
    gemm_kernel<256, 256><<<dim3(128, 4), 256, 0, stream>>>(act3, wc4, G, 512);
    gather_kernel<256><<<NPTS / 4, 256, 0, stream>>>(G, idx, ymin, ymax, stats + OFF4);
    finalize_kernel<256><<<1, 256, 0, stream>>>(stats + OFF4, g4, b4, ss + SS4, 147456.f);
    apply_kernel<256><<<NPTS * 256 / 256, 256, 0, stream>>>(ymin, ymax, ss + SS4, actf, 304);

    // decoder on act1 -> actf cols 256..303
    dec_kernel<<<NPTS, 64, 0, stream>>>(act1, dec_w, zdec, stats + OFFD);
    finalize_kernel<48><<<1, 64, 0, stream>>>(stats + OFFD, dec_g, dec_b, ss + SSD, 16384.f);
    decapply_kernel<<<(NPTS * 48 + 255) / 256, 256, 0, stream>>>(zdec, ss + SSD, actf);

    // fusion GEMM: fus_w (256 x 304) @ actf -> G (16384 x 256)
    gemm_kernel<304, 304><<<dim3(128, 2), 256, 0, stream>>>(actf, fus_w, G, 256);
    fusedred1_kernel<<<64, 256, 0, stream>>>(G, pmax, psum2);
    fusedred2_kernel<<<4, 256, 0, stream>>>(pmax, psum2, hbuf);
    cls_kernel<<<1, 256, 0, stream>>>(hbuf, cls_w1, cls_g, cls_b, cls_w2, out);
}